// Round 3
// baseline (238.563 us; speedup 1.0000x reference)
//
#include <hip/hip_runtime.h>
#include <math.h>

#define B_     64
#define N_     128
#define S_     2048
#define D_     128
#define K_TOP  128
#define CAPB   4096     // per-block candidate cap
#define SELCAP 2048     // per-(batch,side) filtered select list cap

typedef _Float16 f16x8 __attribute__((ext_vector_type(8)));
typedef float    f32x4 __attribute__((ext_vector_type(4)));

union Frag { uint4 u; f16x8 h; };

// Monotone mapping: float total order -> unsigned total order
__device__ __forceinline__ unsigned fkey(float x) {
    unsigned u = __float_as_uint(x);
    return (u & 0x80000000u) ? ~u : (u | 0x80000000u);
}
__device__ __forceinline__ float unkey(unsigned k) {
    unsigned u = (k & 0x80000000u) ? (k & 0x7fffffffu) : ~k;
    return __uint_as_float(u);
}

// 8 fp32 -> 8 fp16 (RNE) packed into uint4
__device__ __forceinline__ uint4 cvt8h(float4 a, float4 b) {
    union { _Float16 h[8]; uint4 u; } r;
    r.h[0] = (_Float16)a.x; r.h[1] = (_Float16)a.y;
    r.h[2] = (_Float16)a.z; r.h[3] = (_Float16)a.w;
    r.h[4] = (_Float16)b.x; r.h[5] = (_Float16)b.y;
    r.h[6] = (_Float16)b.z; r.h[7] = (_Float16)b.w;
    return r.u;
}

// K1: fp16 MFMA GEMM, 128x128 tile, fragments loaded DIRECTLY from global
// to registers (no LDS staging, no barriers in the GEMM): for 16x16x32 the
// A/B fragment of lane (q=lane>>4, m=lane&15) is 8 contiguous floats at
// row = grp*16+m, k = kk*32+q*8 -> two float4 loads + in-register cvt.
// Each element is read by 2 waves (L1-served); HBM fetch unchanged.
// Epilogue: per-row max, threshold = min(rowmax) [provable superset of the
// block top-128], contention-free extraction via wave prefix scan.
__global__ __launch_bounds__(256, 4) void gemm_fused(
    const float* __restrict__ q, const float* __restrict__ dpos,
    const float* __restrict__ dneg, int nb, int b0,
    unsigned* __restrict__ rowmaxLocal,   // [2nb*16*N_] segment maxes
    unsigned* __restrict__ cand,          // [2nb*16*CAPB]
    unsigned* __restrict__ candCnt,       // [2nb*16]
    unsigned* __restrict__ ctr)           // ticket counter for fused loss
{
    __shared__ unsigned rmx[128];
    __shared__ unsigned ctl[2];           // [0]=min rowmax, [1]=cand count
    __shared__ unsigned buf[CAPB];        // 16 KiB candidate buffer

    if (b0 == 0 && blockIdx.x == 0 && blockIdx.z == 0 && threadIdx.x == 0)
        *ctr = 0u;                        // reset ticket for this invocation

    const int z  = blockIdx.z;
    const int bz = (z < nb) ? z : z - nb;
    const float* docs = (z < nb) ? dpos : dneg;
    const int bx = blockIdx.x;
    const int s0 = bx * 128;
    const float* qb = q + (size_t)(b0 + bz) * N_ * D_;
    const float* db = docs + (size_t)(b0 + bz) * S_ * D_;

    const int t    = threadIdx.x;
    const int lane = t & 63;
    const int w    = t >> 6;
    const int quad = lane >> 4;
    const int m    = lane & 15;
    const int Ibase = (w >> 1) << 2;      // A 16-row-group base
    const int Jbase = (w & 1) << 2;       // B 16-row-group base

    f32x4 acc[4][4];
    #pragma unroll
    for (int i = 0; i < 4; ++i)
        #pragma unroll
        for (int j = 0; j < 4; ++j)
            acc[i][j] = f32x4{0.f, 0.f, 0.f, 0.f};

    // row base pointers (kk advances via immediate offsets)
    const float* pa[4];
    const float* pb[4];
    #pragma unroll
    for (int i = 0; i < 4; ++i) {
        pa[i] = qb + (size_t)((Ibase + i) * 16 + m) * D_ + quad * 8;
        pb[i] = db + (size_t)(s0 + (Jbase + i) * 16 + m) * D_ + quad * 8;
    }

    #pragma unroll
    for (int kk = 0; kk < 4; ++kk) {
        Frag af[4], bf[4];
        #pragma unroll
        for (int i = 0; i < 4; ++i) {
            const float* a0 = pa[i] + kk * 32;
            af[i].u = cvt8h(*(const float4*)a0, *(const float4*)(a0 + 4));
            const float* b0p = pb[i] + kk * 32;
            bf[i].u = cvt8h(*(const float4*)b0p, *(const float4*)(b0p + 4));
        }
        #pragma unroll
        for (int i = 0; i < 4; ++i)
            #pragma unroll
            for (int j = 0; j < 4; ++j)
                acc[i][j] = __builtin_amdgcn_mfma_f32_16x16x32_f16(
                    af[i].h, bf[j].h, acc[i][j], 0, 0, 0);
    }

    // ---- epilogue ----
    if (t < 128) rmx[t] = 0u;
    if (t == 0) { ctl[0] = 0xFFFFFFFFu; ctl[1] = 0u; }
    __syncthreads();

    // per-row max (C/D layout: col = lane&15, row = quad*4 + reg)
    #pragma unroll
    for (int i = 0; i < 4; ++i) {
        #pragma unroll
        for (int r = 0; r < 4; ++r) {
            int row = ((Ibase + i) << 4) + (quad << 2) + r;
            unsigned km = max(max(fkey(acc[i][0][r]), fkey(acc[i][1][r])),
                              max(fkey(acc[i][2][r]), fkey(acc[i][3][r])));
            #pragma unroll
            for (int off = 1; off < 16; off <<= 1)
                km = max(km, (unsigned)__shfl_xor((int)km, off, 64));
            if (m == 0) atomicMax(&rmx[row], km);
        }
    }
    __syncthreads();

    const int slot = z * 16 + bx;
    if (t < 128) rowmaxLocal[(size_t)slot * N_ + t] = rmx[t];

    // min over the 128 row maxima
    unsigned mv = (t < 128) ? rmx[t] : 0xFFFFFFFFu;
    #pragma unroll
    for (int off = 32; off > 0; off >>= 1)
        mv = min(mv, (unsigned)__shfl_xor((int)mv, off, 64));
    if ((t & 63) == 0) atomicMin(&ctl[0], mv);
    __syncthreads();
    const unsigned minrm = ctl[0];

    // contention-free extraction: per-thread count -> wave prefix scan ->
    // one atomicAdd per wave -> exclusive write positions
    unsigned cnt = 0;
    #pragma unroll
    for (int i = 0; i < 4; ++i)
        #pragma unroll
        for (int j = 0; j < 4; ++j)
            #pragma unroll
            for (int r = 0; r < 4; ++r)
                cnt += (fkey(acc[i][j][r]) >= minrm) ? 1u : 0u;

    unsigned incl = cnt;
    #pragma unroll
    for (int d = 1; d < 64; d <<= 1) {
        unsigned o = (unsigned)__shfl_up((int)incl, d, 64);
        if (lane >= d) incl += o;
    }
    unsigned base = 0;
    if (lane == 63) base = atomicAdd(&ctl[1], incl);   // incl@63 = wave total
    base = (unsigned)__shfl((int)base, 63, 64);
    unsigned pos = base + (incl - cnt);

    #pragma unroll
    for (int i = 0; i < 4; ++i)
        #pragma unroll
        for (int j = 0; j < 4; ++j)
            #pragma unroll
            for (int r = 0; r < 4; ++r) {
                unsigned u = fkey(acc[i][j][r]);
                if (u >= minrm) {
                    if (pos < CAPB) buf[pos] = u;
                    ++pos;
                }
            }
    __syncthreads();
    unsigned c = min(ctl[1], (unsigned)CAPB);
    for (unsigned i = t; i < c; i += 256) cand[(size_t)slot * CAPB + i] = buf[i];
    if (t == 0) candCnt[slot] = c;
}

// K2: per (batch,side):
//  1) load the 2048 segment maxes; per-row max (over 16 slots) for scoring.
//  2) coarse 2048-bin pass over the segmaxes -> theta = bin lower-bound with
//     suffix-count >= 128, so theta <= s128 (128th-largest segmax) <= T.
//  3) stream candidates, keep >= theta: provable superset of {v >= T}.
//  4) exact 4-round radix-256 select of the 128th largest.
//  5) score from rowmaxes; fused softplus-loss via device-scope ticket.
__global__ __launch_bounds__(256) void select_score(
    const unsigned* __restrict__ cand, const unsigned* __restrict__ candCnt,
    const unsigned* __restrict__ rowmaxLocal, float* __restrict__ sc,
    unsigned* __restrict__ ctr, float* __restrict__ out, int nb, int b0)
{
    __shared__ unsigned seg[2048];        // 16 slots x 128 rows segment maxes
    __shared__ unsigned hist[4096];       // coarse: 2048x2 reps; fine: 256x8 reps
    __shared__ unsigned scanS[256];
    __shared__ unsigned list[SELCAP];
    __shared__ unsigned sctl[4];          // [0]=theta, [1]=count, [2]=pref, [3]=k
    __shared__ float s_sum[4], s_cnt[4];
    __shared__ unsigned sdone;

    const int z   = blockIdx.x;
    const int tid = threadIdx.x;

    for (int i = tid; i < 2048; i += 256)
        seg[i] = rowmaxLocal[(size_t)(z * 16 + (i >> 7)) * N_ + (i & 127)];
    for (int i = tid; i < 4096; i += 256) hist[i] = 0u;
    if (tid == 0) sctl[1] = 0u;
    __syncthreads();

    // per-row max over the 16 slots (row = tid for tid < 128)
    unsigned myrm = 0u;
    if (tid < N_) {
        #pragma unroll
        for (int s = 0; s < 16; ++s) myrm = max(myrm, seg[s * 128 + tid]);
    }

    // coarse histogram of segmaxes (top 11 bits), 2 replicas
    {
        const unsigned rep = tid & 1;
        for (int i = tid; i < 2048; i += 256)
            atomicAdd(&hist[((seg[i] >> 21) << 1) | rep], 1u);
    }
    __syncthreads();
    {
        unsigned s = 0;
        #pragma unroll
        for (int j = 0; j < 8; ++j) {
            int bin = tid * 8 + j;
            s += hist[bin * 2] + hist[bin * 2 + 1];
        }
        scanS[tid] = s;
    }
    __syncthreads();
    #pragma unroll
    for (int d = 1; d < 256; d <<= 1) {
        unsigned v = scanS[tid] + ((tid + d < 256) ? scanS[tid + d] : 0u);
        __syncthreads();
        scanS[tid] = v;
        __syncthreads();
    }
    {
        unsigned Sme = scanS[tid];
        unsigned Snx = (tid == 255) ? 0u : scanS[tid + 1];
        if (Sme >= K_TOP && Snx < K_TOP) {
            unsigned cum = Snx;
            unsigned lb = (unsigned)(tid * 8);
            for (int bin = tid * 8 + 7; bin >= tid * 8; --bin) {
                unsigned hh = hist[bin * 2] + hist[bin * 2 + 1];
                if (cum + hh >= K_TOP) { lb = (unsigned)bin; break; }
                cum += hh;
            }
            sctl[0] = lb << 21;           // theta <= s128 <= T
        }
    }
    __syncthreads();
    const unsigned theta = sctl[0];

    // stream candidates, keep >= theta (~few hundred pass)
    for (int s = 0; s < 16; ++s) {
        const unsigned cnt = candCnt[z * 16 + s];
        const unsigned* src = cand + (size_t)(z * 16 + s) * CAPB;
        for (unsigned i = tid; i < cnt; i += 256) {
            unsigned u = src[i];
            if (u >= theta) {
                unsigned pos = atomicAdd(&sctl[1], 1u);
                if (pos < SELCAP) list[pos] = u;
            }
        }
    }
    __syncthreads();
    const int total = (int)min(sctl[1], (unsigned)SELCAP);

    // exact radix-256 select, 4 rounds, 8 lane-replicas per bin
    if (tid == 0) { sctl[2] = 0u; sctl[3] = (unsigned)K_TOP; }
    __syncthreads();
    for (int r = 0; r < 4; ++r) {
        const int shift = 24 - 8 * r;
        for (int i = tid; i < 2048; i += 256) hist[i] = 0u;
        __syncthreads();
        const unsigned pref = sctl[2];
        const int k = (int)sctl[3];
        const unsigned pm = (r == 0) ? 0u : (0xFFFFFFFFu << (shift + 8));
        for (int i = tid; i < total; i += 256) {
            unsigned u = list[i];
            if ((u & pm) == (pref & pm))
                atomicAdd(&hist[(((u >> shift) & 255u) << 3) | (tid & 7)], 1u);
        }
        __syncthreads();
        unsigned hv = 0;
        #pragma unroll
        for (int j = 0; j < 8; ++j) hv += hist[(tid << 3) | j];
        scanS[tid] = hv;
        __syncthreads();
        #pragma unroll
        for (int d = 1; d < 256; d <<= 1) {
            unsigned v = scanS[tid] + ((tid + d < 256) ? scanS[tid + d] : 0u);
            __syncthreads();
            scanS[tid] = v;
            __syncthreads();
        }
        unsigned Sme = scanS[tid];
        unsigned Snx = (tid == 255) ? 0u : scanS[tid + 1];
        if (Sme >= (unsigned)k && Snx < (unsigned)k) {
            sctl[2] = pref | ((unsigned)tid << shift);
            sctl[3] = (unsigned)(k - (int)Snx);
        }
        __syncthreads();
    }
    const unsigned T = sctl[2];

    // score from the 128 row maxima
    float v = 0.f, c = 0.f;
    if (tid < N_ && myrm >= T) { v = fmaxf(unkey(myrm), 0.f); c = 1.f; }
    #pragma unroll
    for (int off = 32; off > 0; off >>= 1) {
        v += __shfl_xor(v, off, 64);
        c += __shfl_xor(c, off, 64);
    }
    const int wv = tid >> 6;
    if ((tid & 63) == 0) { s_sum[wv] = v; s_cnt[wv] = c; }
    __syncthreads();
    if (tid == 0) {
        float Sv = s_sum[0] + s_sum[1] + s_sum[2] + s_sum[3];
        float Cv = s_cnt[0] + s_cnt[1] + s_cnt[2] + s_cnt[3];
        int b = b0 + ((z < nb) ? z : z - nb);
        int side = (z < nb) ? 0 : 1;
        float scv = Sv / fmaxf(Cv, 0.001f);
        __hip_atomic_store(&sc[side * B_ + b], scv, __ATOMIC_RELEASE,
                           __HIP_MEMORY_SCOPE_AGENT);
        unsigned old = __hip_atomic_fetch_add(ctr, 1u, __ATOMIC_ACQ_REL,
                                              __HIP_MEMORY_SCOPE_AGENT);
        sdone = (old == 2u * B_ - 1u) ? 1u : 0u;
    }
    __syncthreads();
    // last finishing block (device-wide) computes the loss; deterministic
    // fixed-order wave reduce
    if (sdone != 0u && tid < 64) {
        float pos = __hip_atomic_load(&sc[tid], __ATOMIC_ACQUIRE,
                                      __HIP_MEMORY_SCOPE_AGENT);
        float neg = __hip_atomic_load(&sc[B_ + tid], __ATOMIC_ACQUIRE,
                                      __HIP_MEMORY_SCOPE_AGENT);
        float x = neg - pos;
        float sp = (x > 20.f) ? x : log1pf(expf(x));
        #pragma unroll
        for (int o = 32; o > 0; o >>= 1) sp += __shfl_xor(sp, o, 64);
        if (tid == 0) out[0] = sp * (1.f / B_);
    }
}

extern "C" void kernel_launch(void* const* d_in, const int* in_sizes, int n_in,
                              void* d_out, int out_size, void* d_ws, size_t ws_size,
                              hipStream_t stream) {
    const float* q    = (const float*)d_in[0];
    const float* dpos = (const float*)d_in[1];
    const float* dneg = (const float*)d_in[2];
    float* out = (float*)d_out;
    char* ws = (char*)d_ws;

    // per-batch bytes (x2 sides): rowmaxLocal 16*128 + cand 16*CAPB + candCnt 16
    const size_t per_batch = 2ull * (16 * N_ + 16 * CAPB + 16) * 4;
    const size_t fixed = 1024;
    size_t avail = (ws_size > fixed) ? (ws_size - fixed) : 0;
    int Bc = (int)(avail / per_batch);
    if (Bc > B_) Bc = B_;
    if (Bc < 1) Bc = 1;

    char* p = ws;
    float*    sc          = (float*)p;    p += 512;   // 2*B_ floats
    unsigned* ctr         = (unsigned*)p; p += 512;   // ticket counter
    unsigned* rowmaxLocal = (unsigned*)p; p += (size_t)2 * Bc * 16 * N_ * 4;
    unsigned* candCnt     = (unsigned*)p; p += (size_t)2 * Bc * 16 * 4;
    unsigned* cand        = (unsigned*)p; p += (size_t)2 * Bc * 16 * CAPB * 4;

    for (int b0 = 0; b0 < B_; b0 += Bc) {
        int nb = (B_ - b0 < Bc) ? (B_ - b0) : Bc;
        gemm_fused<<<dim3(S_ / 128, 1, 2 * nb), 256, 0, stream>>>(
            q, dpos, dneg, nb, b0, rowmaxLocal, cand, candCnt, ctr);
        select_score<<<2 * nb, 256, 0, stream>>>(
            cand, candCnt, rowmaxLocal, sc, ctr, out, nb, b0);
    }
}

// Round 4
// 215.983 us; speedup vs baseline: 1.1045x; 1.1045x over previous
//
#include <hip/hip_runtime.h>
#include <math.h>

#define B_     64
#define N_     128
#define S_     2048
#define D_     128
#define K_TOP  128
#define CAPB   4096     // per-block candidate cap
#define SELCAP 2048     // per-(batch,side) filtered select list cap

typedef _Float16 f16x8 __attribute__((ext_vector_type(8)));
typedef float    f32x4 __attribute__((ext_vector_type(4)));

union Frag { uint4 u; f16x8 h; };

// Monotone mapping: float total order -> unsigned total order
__device__ __forceinline__ unsigned fkey(float x) {
    unsigned u = __float_as_uint(x);
    return (u & 0x80000000u) ? ~u : (u | 0x80000000u);
}
__device__ __forceinline__ float unkey(unsigned k) {
    unsigned u = (k & 0x80000000u) ? (k & 0x7fffffffu) : ~k;
    return __uint_as_float(u);
}

// 8 fp32 -> 8 fp16 (RNE) packed into uint4
__device__ __forceinline__ uint4 cvt8h(float4 a, float4 b) {
    union { _Float16 h[8]; uint4 u; } r;
    r.h[0] = (_Float16)a.x; r.h[1] = (_Float16)a.y;
    r.h[2] = (_Float16)a.z; r.h[3] = (_Float16)a.w;
    r.h[4] = (_Float16)b.x; r.h[5] = (_Float16)b.y;
    r.h[6] = (_Float16)b.z; r.h[7] = (_Float16)b.w;
    return r.u;
}

// K1: fp16 MFMA GEMM, 128x128 tile, BK=64 (2 iters), LDS-staged.
// COALESCED staging: chunk ci -> row = ci>>3, oct = ci&7, so consecutive
// lanes read consecutive 32B along k (a wave covers 8 rows x 256B
// contiguous). LDS chunk layout [grp][oct][m] with XOR swizzle m^oct so
// the oct-fastest ds_write_b128 spreads across banks; the fragment read
// (lane (quad,m) needs row grp*16+m, k-octet ks*4+quad) applies the same
// XOR. Frag data delivered to each lane is identical to the previous
// (verified) mapping -- only the LDS addresses changed.
// Epilogue: per-row max, threshold = min(rowmax) [the 128 rowmaxes are
// 128 distinct elements of the block, so block's 128th-largest >=
// min(rowmax) => {v >= min(rowmax)} superset of block top-128], then
// contention-free extraction via wave prefix scan.
__global__ __launch_bounds__(256) void gemm_fused(
    const float* __restrict__ q, const float* __restrict__ dpos,
    const float* __restrict__ dneg, int nb, int b0,
    unsigned* __restrict__ rowmaxLocal,   // [2nb*16*N_] segment maxes
    unsigned* __restrict__ cand,          // [2nb*16*CAPB]
    unsigned* __restrict__ candCnt,       // [2nb*16]
    unsigned* __restrict__ ctr)           // ticket counter for fused loss
{
    __shared__ uint4 sh4[2048];           // exactly 32 KiB
    if (b0 == 0 && blockIdx.x == 0 && blockIdx.z == 0 && threadIdx.x == 0)
        *ctr = 0u;                        // reset ticket for this invocation

    const int z  = blockIdx.z;
    const int bz = (z < nb) ? z : z - nb;
    const float* docs = (z < nb) ? dpos : dneg;
    const int bx = blockIdx.x;
    const int s0 = bx * 128;
    const float* qb = q + (size_t)(b0 + bz) * N_ * D_;
    const float* db = docs + (size_t)(b0 + bz) * S_ * D_;

    const int t    = threadIdx.x;
    const int lane = t & 63;
    const int w    = t >> 6;
    const int quad = lane >> 4;
    const int m    = lane & 15;
    const int Ibase = (w >> 1) << 2;
    const int Jbase = (w & 1) << 2;

    f32x4 acc[4][4];
    #pragma unroll
    for (int i = 0; i < 4; ++i)
        #pragma unroll
        for (int j = 0; j < 4; ++j)
            acc[i][j] = f32x4{0.f, 0.f, 0.f, 0.f};

    for (int k0 = 0; k0 < D_; k0 += 64) {
        // coalesced stage: ci -> row=ci>>3, oct=ci&7; swizzled LDS store
        #pragma unroll
        for (int p = 0; p < 4; ++p) {
            int ci  = t + p * 256;
            int row = ci >> 3;
            int oct = ci & 7;
            int idx = ((row >> 4) << 7) + (oct << 4) + ((row & 15) ^ oct);
            const float* ga = qb + (size_t)row * D_ + k0 + oct * 8;
            sh4[idx] = cvt8h(*(const float4*)ga, *(const float4*)(ga + 4));
            const float* gb = db + (size_t)(s0 + row) * D_ + k0 + oct * 8;
            sh4[1024 + idx] = cvt8h(*(const float4*)gb, *(const float4*)(gb + 4));
        }
        __syncthreads();
        #pragma unroll
        for (int ks = 0; ks < 2; ++ks) {
            const int oa = ks * 4 + quad;
            const int sw = (oa << 4) + (m ^ oa);
            Frag af[4], bf[4];
            #pragma unroll
            for (int i = 0; i < 4; ++i) {
                af[i].u = sh4[((Ibase + i) << 7) + sw];
                bf[i].u = sh4[1024 + ((Jbase + i) << 7) + sw];
            }
            #pragma unroll
            for (int i = 0; i < 4; ++i)
                #pragma unroll
                for (int j = 0; j < 4; ++j)
                    acc[i][j] = __builtin_amdgcn_mfma_f32_16x16x32_f16(
                        af[i].h, bf[j].h, acc[i][j], 0, 0, 0);
        }
        __syncthreads();
    }

    // ---- epilogue scratch, aliased into sh4 (words) ----
    unsigned* rmx = (unsigned*)sh4;         // [0,128): row maxima
    unsigned* ctl = ((unsigned*)sh4) + 128; // [128]=min rowmax, [129]=count
    unsigned* buf = ((unsigned*)sh4) + 256; // [256, 256+CAPB): candidates
    if (t < 128) rmx[t] = 0u;
    if (t == 0) { ctl[0] = 0xFFFFFFFFu; ctl[1] = 0u; }
    __syncthreads();

    // per-row max (C/D layout: col = lane&15, row = quad*4 + reg)
    #pragma unroll
    for (int i = 0; i < 4; ++i) {
        #pragma unroll
        for (int r = 0; r < 4; ++r) {
            int row = ((Ibase + i) << 4) + (quad << 2) + r;
            unsigned km = max(max(fkey(acc[i][0][r]), fkey(acc[i][1][r])),
                              max(fkey(acc[i][2][r]), fkey(acc[i][3][r])));
            #pragma unroll
            for (int off = 1; off < 16; off <<= 1)
                km = max(km, (unsigned)__shfl_xor((int)km, off, 64));
            if (m == 0) atomicMax(&rmx[row], km);
        }
    }
    __syncthreads();

    const int slot = z * 16 + bx;
    if (t < 128) rowmaxLocal[(size_t)slot * N_ + t] = rmx[t];

    // min over the 128 row maxima
    unsigned mv = (t < 128) ? rmx[t] : 0xFFFFFFFFu;
    #pragma unroll
    for (int off = 32; off > 0; off >>= 1)
        mv = min(mv, (unsigned)__shfl_xor((int)mv, off, 64));
    if ((t & 63) == 0) atomicMin(&ctl[0], mv);
    __syncthreads();
    const unsigned minrm = ctl[0];

    // contention-free extraction: per-thread count -> wave prefix scan ->
    // one atomicAdd per wave -> exclusive write positions
    unsigned cnt = 0;
    #pragma unroll
    for (int i = 0; i < 4; ++i)
        #pragma unroll
        for (int j = 0; j < 4; ++j)
            #pragma unroll
            for (int r = 0; r < 4; ++r)
                cnt += (fkey(acc[i][j][r]) >= minrm) ? 1u : 0u;

    unsigned incl = cnt;
    #pragma unroll
    for (int d = 1; d < 64; d <<= 1) {
        unsigned o = (unsigned)__shfl_up((int)incl, d, 64);
        if (lane >= d) incl += o;
    }
    unsigned base = 0;
    if (lane == 63) base = atomicAdd(&ctl[1], incl);   // incl@63 = wave total
    base = (unsigned)__shfl((int)base, 63, 64);
    unsigned pos = base + (incl - cnt);

    #pragma unroll
    for (int i = 0; i < 4; ++i)
        #pragma unroll
        for (int j = 0; j < 4; ++j)
            #pragma unroll
            for (int r = 0; r < 4; ++r) {
                unsigned u = fkey(acc[i][j][r]);
                if (u >= minrm) {
                    if (pos < CAPB) buf[pos] = u;
                    ++pos;
                }
            }
    __syncthreads();
    unsigned c = min(ctl[1], (unsigned)CAPB);
    for (unsigned i = t; i < c; i += 256) cand[(size_t)slot * CAPB + i] = buf[i];
    if (t == 0) candCnt[slot] = c;
}

// K2: per (batch,side):
//  1) load the 2048 segment maxes; per-row max (over 16 slots) for scoring.
//  2) coarse 2048-bin pass over the segmaxes -> theta = bin lower-bound with
//     suffix-count >= 128, so theta <= s128 (128th-largest segmax) <= T.
//  3) stream candidates, keep >= theta: provable superset of {v >= T}.
//  4) exact 4-round radix-256 select of the 128th largest.
//  5) score from rowmaxes; fused softplus-loss via device-scope ticket.
__global__ __launch_bounds__(256) void select_score(
    const unsigned* __restrict__ cand, const unsigned* __restrict__ candCnt,
    const unsigned* __restrict__ rowmaxLocal, float* __restrict__ sc,
    unsigned* __restrict__ ctr, float* __restrict__ out, int nb, int b0)
{
    __shared__ unsigned seg[2048];        // 16 slots x 128 rows segment maxes
    __shared__ unsigned hist[4096];       // coarse: 2048x2 reps; fine: 256x8 reps
    __shared__ unsigned scanS[256];
    __shared__ unsigned list[SELCAP];
    __shared__ unsigned sctl[4];          // [0]=theta, [1]=count, [2]=pref, [3]=k
    __shared__ float s_sum[4], s_cnt[4];
    __shared__ unsigned sdone;

    const int z   = blockIdx.x;
    const int tid = threadIdx.x;

    for (int i = tid; i < 2048; i += 256)
        seg[i] = rowmaxLocal[(size_t)(z * 16 + (i >> 7)) * N_ + (i & 127)];
    for (int i = tid; i < 4096; i += 256) hist[i] = 0u;
    if (tid == 0) sctl[1] = 0u;
    __syncthreads();

    // per-row max over the 16 slots (row = tid for tid < 128)
    unsigned myrm = 0u;
    if (tid < N_) {
        #pragma unroll
        for (int s = 0; s < 16; ++s) myrm = max(myrm, seg[s * 128 + tid]);
    }

    // coarse histogram of segmaxes (top 11 bits), 2 replicas
    {
        const unsigned rep = tid & 1;
        for (int i = tid; i < 2048; i += 256)
            atomicAdd(&hist[((seg[i] >> 21) << 1) | rep], 1u);
    }
    __syncthreads();
    {
        unsigned s = 0;
        #pragma unroll
        for (int j = 0; j < 8; ++j) {
            int bin = tid * 8 + j;
            s += hist[bin * 2] + hist[bin * 2 + 1];
        }
        scanS[tid] = s;
    }
    __syncthreads();
    #pragma unroll
    for (int d = 1; d < 256; d <<= 1) {
        unsigned v = scanS[tid] + ((tid + d < 256) ? scanS[tid + d] : 0u);
        __syncthreads();
        scanS[tid] = v;
        __syncthreads();
    }
    {
        unsigned Sme = scanS[tid];
        unsigned Snx = (tid == 255) ? 0u : scanS[tid + 1];
        if (Sme >= K_TOP && Snx < K_TOP) {
            unsigned cum = Snx;
            unsigned lb = (unsigned)(tid * 8);
            for (int bin = tid * 8 + 7; bin >= tid * 8; --bin) {
                unsigned hh = hist[bin * 2] + hist[bin * 2 + 1];
                if (cum + hh >= K_TOP) { lb = (unsigned)bin; break; }
                cum += hh;
            }
            sctl[0] = lb << 21;           // theta <= s128 <= T
        }
    }
    __syncthreads();
    const unsigned theta = sctl[0];

    // stream candidates, keep >= theta (~few hundred pass)
    for (int s = 0; s < 16; ++s) {
        const unsigned cnt = candCnt[z * 16 + s];
        const unsigned* src = cand + (size_t)(z * 16 + s) * CAPB;
        for (unsigned i = tid; i < cnt; i += 256) {
            unsigned u = src[i];
            if (u >= theta) {
                unsigned pos = atomicAdd(&sctl[1], 1u);
                if (pos < SELCAP) list[pos] = u;
            }
        }
    }
    __syncthreads();
    const int total = (int)min(sctl[1], (unsigned)SELCAP);

    // exact radix-256 select, 4 rounds, 8 lane-replicas per bin
    if (tid == 0) { sctl[2] = 0u; sctl[3] = (unsigned)K_TOP; }
    __syncthreads();
    for (int r = 0; r < 4; ++r) {
        const int shift = 24 - 8 * r;
        for (int i = tid; i < 2048; i += 256) hist[i] = 0u;
        __syncthreads();
        const unsigned pref = sctl[2];
        const int k = (int)sctl[3];
        const unsigned pm = (r == 0) ? 0u : (0xFFFFFFFFu << (shift + 8));
        for (int i = tid; i < total; i += 256) {
            unsigned u = list[i];
            if ((u & pm) == (pref & pm))
                atomicAdd(&hist[(((u >> shift) & 255u) << 3) | (tid & 7)], 1u);
        }
        __syncthreads();
        unsigned hv = 0;
        #pragma unroll
        for (int j = 0; j < 8; ++j) hv += hist[(tid << 3) | j];
        scanS[tid] = hv;
        __syncthreads();
        #pragma unroll
        for (int d = 1; d < 256; d <<= 1) {
            unsigned v = scanS[tid] + ((tid + d < 256) ? scanS[tid + d] : 0u);
            __syncthreads();
            scanS[tid] = v;
            __syncthreads();
        }
        unsigned Sme = scanS[tid];
        unsigned Snx = (tid == 255) ? 0u : scanS[tid + 1];
        if (Sme >= (unsigned)k && Snx < (unsigned)k) {
            sctl[2] = pref | ((unsigned)tid << shift);
            sctl[3] = (unsigned)(k - (int)Snx);
        }
        __syncthreads();
    }
    const unsigned T = sctl[2];

    // score from the 128 row maxima
    float v = 0.f, c = 0.f;
    if (tid < N_ && myrm >= T) { v = fmaxf(unkey(myrm), 0.f); c = 1.f; }
    #pragma unroll
    for (int off = 32; off > 0; off >>= 1) {
        v += __shfl_xor(v, off, 64);
        c += __shfl_xor(c, off, 64);
    }
    const int wv = tid >> 6;
    if ((tid & 63) == 0) { s_sum[wv] = v; s_cnt[wv] = c; }
    __syncthreads();
    if (tid == 0) {
        float Sv = s_sum[0] + s_sum[1] + s_sum[2] + s_sum[3];
        float Cv = s_cnt[0] + s_cnt[1] + s_cnt[2] + s_cnt[3];
        int b = b0 + ((z < nb) ? z : z - nb);
        int side = (z < nb) ? 0 : 1;
        float scv = Sv / fmaxf(Cv, 0.001f);
        __hip_atomic_store(&sc[side * B_ + b], scv, __ATOMIC_RELEASE,
                           __HIP_MEMORY_SCOPE_AGENT);
        unsigned old = __hip_atomic_fetch_add(ctr, 1u, __ATOMIC_ACQ_REL,
                                              __HIP_MEMORY_SCOPE_AGENT);
        sdone = (old == 2u * B_ - 1u) ? 1u : 0u;
    }
    __syncthreads();
    // last finishing block (device-wide) computes the loss; deterministic
    // fixed-order wave reduce
    if (sdone != 0u && tid < 64) {
        float pos = __hip_atomic_load(&sc[tid], __ATOMIC_ACQUIRE,
                                      __HIP_MEMORY_SCOPE_AGENT);
        float neg = __hip_atomic_load(&sc[B_ + tid], __ATOMIC_ACQUIRE,
                                      __HIP_MEMORY_SCOPE_AGENT);
        float x = neg - pos;
        float sp = (x > 20.f) ? x : log1pf(expf(x));
        #pragma unroll
        for (int o = 32; o > 0; o >>= 1) sp += __shfl_xor(sp, o, 64);
        if (tid == 0) out[0] = sp * (1.f / B_);
    }
}

extern "C" void kernel_launch(void* const* d_in, const int* in_sizes, int n_in,
                              void* d_out, int out_size, void* d_ws, size_t ws_size,
                              hipStream_t stream) {
    const float* q    = (const float*)d_in[0];
    const float* dpos = (const float*)d_in[1];
    const float* dneg = (const float*)d_in[2];
    float* out = (float*)d_out;
    char* ws = (char*)d_ws;

    // per-batch bytes (x2 sides): rowmaxLocal 16*128 + cand 16*CAPB + candCnt 16
    const size_t per_batch = 2ull * (16 * N_ + 16 * CAPB + 16) * 4;
    const size_t fixed = 1024;
    size_t avail = (ws_size > fixed) ? (ws_size - fixed) : 0;
    int Bc = (int)(avail / per_batch);
    if (Bc > B_) Bc = B_;
    if (Bc < 1) Bc = 1;

    char* p = ws;
    float*    sc          = (float*)p;    p += 512;   // 2*B_ floats
    unsigned* ctr         = (unsigned*)p; p += 512;   // ticket counter
    unsigned* rowmaxLocal = (unsigned*)p; p += (size_t)2 * Bc * 16 * N_ * 4;
    unsigned* candCnt     = (unsigned*)p; p += (size_t)2 * Bc * 16 * 4;
    unsigned* cand        = (unsigned*)p; p += (size_t)2 * Bc * 16 * CAPB * 4;

    for (int b0 = 0; b0 < B_; b0 += Bc) {
        int nb = (B_ - b0 < Bc) ? (B_ - b0) : Bc;
        gemm_fused<<<dim3(S_ / 128, 1, 2 * nb), 256, 0, stream>>>(
            q, dpos, dneg, nb, b0, rowmaxLocal, cand, candCnt, ctr);
        select_score<<<2 * nb, 256, 0, stream>>>(
            cand, candCnt, rowmaxLocal, sc, ctr, out, nb, b0);
    }
}

// Round 5
// 211.233 us; speedup vs baseline: 1.1294x; 1.0225x over previous
//
#include <hip/hip_runtime.h>
#include <math.h>

#define B_     64
#define N_     128
#define S_     2048
#define D_     128
#define K_TOP  128
#define CAPB   2048     // per-block LDS candidate buffer (expected ~300)
#define SHCAP  12288    // shared per-(batch,side) candidate list cap

typedef _Float16 f16x8 __attribute__((ext_vector_type(8)));
typedef float    f32x4 __attribute__((ext_vector_type(4)));

union Frag { uint4 u; f16x8 h; };

// Monotone mapping: float total order -> unsigned total order
__device__ __forceinline__ unsigned fkey(float x) {
    unsigned u = __float_as_uint(x);
    return (u & 0x80000000u) ? ~u : (u | 0x80000000u);
}
__device__ __forceinline__ float unkey(unsigned k) {
    unsigned u = (k & 0x80000000u) ? (k & 0x7fffffffu) : ~k;
    return __uint_as_float(u);
}

// 8 fp32 -> 8 fp16 (RNE) packed into uint4
__device__ __forceinline__ uint4 cvt8h(float4 a, float4 b) {
    union { _Float16 h[8]; uint4 u; } r;
    r.h[0] = (_Float16)a.x; r.h[1] = (_Float16)a.y;
    r.h[2] = (_Float16)a.z; r.h[3] = (_Float16)a.w;
    r.h[4] = (_Float16)b.x; r.h[5] = (_Float16)b.y;
    r.h[6] = (_Float16)b.z; r.h[7] = (_Float16)b.w;
    return r.u;
}

// K1: fp16 MFMA GEMM, 128x128 tile, BK=64, LDS-staged (R4 structure kept:
// coalesced global stage, XOR-swizzled LDS, 0 bank conflicts).
// Epilogue: per-row max; threshold = min(rowmax) [128 rowmaxes are 128
// distinct elements of the block => block's 128th-largest >= min(rowmax)
// => {v >= min(rowmax)} is a superset of the block's top-128]; wave
// prefix-scan compaction into LDS; ONE global atomicAdd reserves a range
// in the per-(batch,side) SHARED list; coalesced copy-out.
__global__ __launch_bounds__(256) void gemm_fused(
    const float* __restrict__ q, const float* __restrict__ dpos,
    const float* __restrict__ dneg, int nb, int b0,
    unsigned* __restrict__ rowmaxLocal,   // [2nb*16*N_] segment maxes
    unsigned* __restrict__ cand,          // [2nb*SHCAP] shared lists
    unsigned* __restrict__ candCnt)       // [2nb] shared counters (pre-zeroed)
{
    __shared__ uint4 sh4[2048];           // exactly 32 KiB
    const int z  = blockIdx.z;
    const int bz = (z < nb) ? z : z - nb;
    const float* docs = (z < nb) ? dpos : dneg;
    const int bx = blockIdx.x;
    const int s0 = bx * 128;
    const float* qb = q + (size_t)(b0 + bz) * N_ * D_;
    const float* db = docs + (size_t)(b0 + bz) * S_ * D_;

    const int t    = threadIdx.x;
    const int lane = t & 63;
    const int w    = t >> 6;
    const int quad = lane >> 4;
    const int m    = lane & 15;
    const int Ibase = (w >> 1) << 2;
    const int Jbase = (w & 1) << 2;

    f32x4 acc[4][4];
    #pragma unroll
    for (int i = 0; i < 4; ++i)
        #pragma unroll
        for (int j = 0; j < 4; ++j)
            acc[i][j] = f32x4{0.f, 0.f, 0.f, 0.f};

    for (int k0 = 0; k0 < D_; k0 += 64) {
        // coalesced stage: ci -> row=ci>>3, oct=ci&7; swizzled LDS store
        #pragma unroll
        for (int p = 0; p < 4; ++p) {
            int ci  = t + p * 256;
            int row = ci >> 3;
            int oct = ci & 7;
            int idx = ((row >> 4) << 7) + (oct << 4) + ((row & 15) ^ oct);
            const float* ga = qb + (size_t)row * D_ + k0 + oct * 8;
            sh4[idx] = cvt8h(*(const float4*)ga, *(const float4*)(ga + 4));
            const float* gb = db + (size_t)(s0 + row) * D_ + k0 + oct * 8;
            sh4[1024 + idx] = cvt8h(*(const float4*)gb, *(const float4*)(gb + 4));
        }
        __syncthreads();
        #pragma unroll
        for (int ks = 0; ks < 2; ++ks) {
            const int oa = ks * 4 + quad;
            const int sw = (oa << 4) + (m ^ oa);
            Frag af[4], bf[4];
            #pragma unroll
            for (int i = 0; i < 4; ++i) {
                af[i].u = sh4[((Ibase + i) << 7) + sw];
                bf[i].u = sh4[1024 + ((Jbase + i) << 7) + sw];
            }
            #pragma unroll
            for (int i = 0; i < 4; ++i)
                #pragma unroll
                for (int j = 0; j < 4; ++j)
                    acc[i][j] = __builtin_amdgcn_mfma_f32_16x16x32_f16(
                        af[i].h, bf[j].h, acc[i][j], 0, 0, 0);
        }
        __syncthreads();
    }

    // ---- epilogue scratch, aliased into sh4 (words) ----
    unsigned* rmx = (unsigned*)sh4;         // [0,128): row maxima
    unsigned* ctl = ((unsigned*)sh4) + 128; // [128]=minrm, [129]=cnt, [130]=base
    unsigned* buf = ((unsigned*)sh4) + 256; // [256, 256+CAPB)
    if (t < 128) rmx[t] = 0u;
    if (t == 0) { ctl[0] = 0xFFFFFFFFu; ctl[1] = 0u; }
    __syncthreads();

    // per-row max (C/D layout: col = lane&15, row = quad*4 + reg)
    #pragma unroll
    for (int i = 0; i < 4; ++i) {
        #pragma unroll
        for (int r = 0; r < 4; ++r) {
            int row = ((Ibase + i) << 4) + (quad << 2) + r;
            unsigned km = max(max(fkey(acc[i][0][r]), fkey(acc[i][1][r])),
                              max(fkey(acc[i][2][r]), fkey(acc[i][3][r])));
            #pragma unroll
            for (int off = 1; off < 16; off <<= 1)
                km = max(km, (unsigned)__shfl_xor((int)km, off, 64));
            if (m == 0) atomicMax(&rmx[row], km);
        }
    }
    __syncthreads();

    const int slot = z * 16 + bx;
    if (t < 128) rowmaxLocal[(size_t)slot * N_ + t] = rmx[t];

    // min over the 128 row maxima
    unsigned mv = (t < 128) ? rmx[t] : 0xFFFFFFFFu;
    #pragma unroll
    for (int off = 32; off > 0; off >>= 1)
        mv = min(mv, (unsigned)__shfl_xor((int)mv, off, 64));
    if ((t & 63) == 0) atomicMin(&ctl[0], mv);
    __syncthreads();
    const unsigned minrm = ctl[0];

    // contention-free compaction: per-thread count -> wave prefix scan ->
    // one LDS atomicAdd per wave -> exclusive write positions
    unsigned cnt = 0;
    #pragma unroll
    for (int i = 0; i < 4; ++i)
        #pragma unroll
        for (int j = 0; j < 4; ++j)
            #pragma unroll
            for (int r = 0; r < 4; ++r)
                cnt += (fkey(acc[i][j][r]) >= minrm) ? 1u : 0u;

    unsigned incl = cnt;
    #pragma unroll
    for (int d = 1; d < 64; d <<= 1) {
        unsigned o = (unsigned)__shfl_up((int)incl, d, 64);
        if (lane >= d) incl += o;
    }
    unsigned base = 0;
    if (lane == 63) base = atomicAdd(&ctl[1], incl);   // incl@63 = wave total
    base = (unsigned)__shfl((int)base, 63, 64);
    unsigned pos = base + (incl - cnt);

    #pragma unroll
    for (int i = 0; i < 4; ++i)
        #pragma unroll
        for (int j = 0; j < 4; ++j)
            #pragma unroll
            for (int r = 0; r < 4; ++r) {
                unsigned u = fkey(acc[i][j][r]);
                if (u >= minrm) {
                    if (pos < CAPB) buf[pos] = u;
                    ++pos;
                }
            }
    __syncthreads();
    // reserve a range in the shared (batch,side) list; coalesced copy-out
    if (t == 0) ctl[2] = atomicAdd(&candCnt[z], min(ctl[1], (unsigned)CAPB));
    __syncthreads();
    const unsigned c  = min(ctl[1], (unsigned)CAPB);
    const unsigned gb = ctl[2];
    unsigned* gdst = cand + (size_t)z * SHCAP;
    for (unsigned i = t; i < c; i += 256) {
        unsigned p = gb + i;
        if (p < SHCAP) gdst[p] = buf[i];
    }
}

// K2: one block per (batch,side).
//  1) copy the shared candidate list (~4600, superset of global top-128)
//     into LDS -- plain coalesced copy, no atomics, no filter.
//  2) exact 4-round radix-256 select of the 128th-largest key T.
//     Per round: 16-replica histogram + warp shfl_down suffix scan
//     (Snx = Sme - own-bin, so no neighbor read) -- 4 barriers/round.
//  3) per-row max over the 16 slots; score; fused softplus-loss via
//     device-scope ticket (identical reduce order to previous rounds).
__global__ __launch_bounds__(256) void select_score(
    const unsigned* __restrict__ cand, const unsigned* __restrict__ candCnt,
    const unsigned* __restrict__ rowmaxLocal, float* __restrict__ sc,
    unsigned* __restrict__ ctr, float* __restrict__ out, int nb, int b0)
{
    __shared__ unsigned list[SHCAP];      // 48 KiB
    __shared__ unsigned hist[4096];       // 256 bins x 16 replicas
    __shared__ unsigned wtot[4];
    __shared__ unsigned sctl[2];          // [0]=pref, [1]=k
    __shared__ float s_sum[4], s_cnt[4];
    __shared__ unsigned sdone;

    const int z    = blockIdx.x;
    const int tid  = threadIdx.x;
    const int lane = tid & 63;
    const int wp   = tid >> 6;

    const unsigned cnt = min(candCnt[z], (unsigned)SHCAP);
    for (unsigned i = tid; i < cnt; i += 256)
        list[i] = cand[(size_t)z * SHCAP + i];

    // per-row max over the 16 slots (row = tid for tid < 128)
    unsigned myrm = 0u;
    if (tid < N_) {
        #pragma unroll
        for (int s = 0; s < 16; ++s)
            myrm = max(myrm, rowmaxLocal[(size_t)(z * 16 + s) * N_ + tid]);
    }
    if (tid == 0) { sctl[0] = 0u; sctl[1] = (unsigned)K_TOP; }
    __syncthreads();

    for (int r = 0; r < 4; ++r) {
        const int shift = 24 - 8 * r;
        for (int i = tid; i < 4096; i += 256) hist[i] = 0u;
        __syncthreads();
        const unsigned pref = sctl[0];
        const unsigned k    = sctl[1];
        const unsigned pm = (r == 0) ? 0u : (0xFFFFFFFFu << (shift + 8));
        for (unsigned i = tid; i < cnt; i += 256) {
            unsigned u = list[i];
            if ((u & pm) == (pref & pm))
                atomicAdd(&hist[(((u >> shift) & 255u) << 4) | (tid & 15)], 1u);
        }
        __syncthreads();
        unsigned hv = 0;
        #pragma unroll
        for (int j = 0; j < 16; ++j) hv += hist[(tid << 4) | j];
        // warp inclusive suffix scan over the 64 bins owned by this warp
        unsigned v = hv;
        #pragma unroll
        for (int d = 1; d < 64; d <<= 1) {
            unsigned o = (unsigned)__shfl_down((int)v, d, 64);
            if (lane + d < 64) v += o;
        }
        if (lane == 0) wtot[wp] = v;      // warp total (suffix from lane 0)
        __syncthreads();
        unsigned add = 0;
        #pragma unroll
        for (int w2 = 0; w2 < 4; ++w2)
            if (w2 > wp) add += wtot[w2];
        unsigned Sme = v + add;           // suffix sum including bin tid
        unsigned Snx = Sme - hv;          // suffix excluding bin tid
        if (Sme >= k && Snx < k) {
            sctl[0] = pref | ((unsigned)tid << shift);
            sctl[1] = k - Snx;
        }
        __syncthreads();
    }
    const unsigned T = sctl[0];

    // score from the 128 row maxima (reduce order identical to prior rounds)
    float v = 0.f, c = 0.f;
    if (tid < N_ && myrm >= T) { v = fmaxf(unkey(myrm), 0.f); c = 1.f; }
    #pragma unroll
    for (int off = 32; off > 0; off >>= 1) {
        v += __shfl_xor(v, off, 64);
        c += __shfl_xor(c, off, 64);
    }
    if ((tid & 63) == 0) { s_sum[wp] = v; s_cnt[wp] = c; }
    __syncthreads();
    if (tid == 0) {
        float Sv = s_sum[0] + s_sum[1] + s_sum[2] + s_sum[3];
        float Cv = s_cnt[0] + s_cnt[1] + s_cnt[2] + s_cnt[3];
        int b = b0 + ((z < nb) ? z : z - nb);
        int side = (z < nb) ? 0 : 1;
        float scv = Sv / fmaxf(Cv, 0.001f);
        __hip_atomic_store(&sc[side * B_ + b], scv, __ATOMIC_RELEASE,
                           __HIP_MEMORY_SCOPE_AGENT);
        unsigned old = __hip_atomic_fetch_add(ctr, 1u, __ATOMIC_ACQ_REL,
                                              __HIP_MEMORY_SCOPE_AGENT);
        sdone = (old == 2u * B_ - 1u) ? 1u : 0u;
    }
    __syncthreads();
    // last finishing block (device-wide) computes the loss
    if (sdone != 0u && tid < 64) {
        float pos = __hip_atomic_load(&sc[tid], __ATOMIC_ACQUIRE,
                                      __HIP_MEMORY_SCOPE_AGENT);
        float neg = __hip_atomic_load(&sc[B_ + tid], __ATOMIC_ACQUIRE,
                                      __HIP_MEMORY_SCOPE_AGENT);
        float x = neg - pos;
        float sp = (x > 20.f) ? x : log1pf(expf(x));
        #pragma unroll
        for (int o = 32; o > 0; o >>= 1) sp += __shfl_xor(sp, o, 64);
        if (tid == 0) out[0] = sp * (1.f / B_);
    }
}

extern "C" void kernel_launch(void* const* d_in, const int* in_sizes, int n_in,
                              void* d_out, int out_size, void* d_ws, size_t ws_size,
                              hipStream_t stream) {
    const float* q    = (const float*)d_in[0];
    const float* dpos = (const float*)d_in[1];
    const float* dneg = (const float*)d_in[2];
    float* out = (float*)d_out;
    char* ws = (char*)d_ws;

    // per-batch bytes (x2 sides): rowmax 16*128*4 + shared cand SHCAP*4
    const size_t per_batch = 2ull * (16 * N_ + SHCAP) * 4;
    const size_t fixed = 512 + 256 + 512;
    size_t avail = (ws_size > fixed) ? (ws_size - fixed) : 0;
    int Bc = (int)(avail / per_batch);
    if (Bc > B_) Bc = B_;
    if (Bc < 1) Bc = 1;

    char* p = ws;
    float*    sc          = (float*)p;    p += 512;   // 2*B_ floats
    unsigned* ctr         = (unsigned*)p; p += 256;   // ticket counter
    unsigned* candCnt     = (unsigned*)p; p += 512;   // up to 128 counters
    unsigned* rowmaxLocal = (unsigned*)p; p += (size_t)2 * Bc * 16 * N_ * 4;
    unsigned* cand        = (unsigned*)p; p += (size_t)2 * Bc * SHCAP * 4;

    hipMemsetAsync(ctr, 0, 256, stream);
    for (int b0 = 0; b0 < B_; b0 += Bc) {
        int nb = (B_ - b0 < Bc) ? (B_ - b0) : Bc;
        hipMemsetAsync(candCnt, 0, (size_t)2 * nb * 4, stream);
        gemm_fused<<<dim3(S_ / 128, 1, 2 * nb), 256, 0, stream>>>(
            q, dpos, dneg, nb, b0, rowmaxLocal, cand, candCnt);
        select_score<<<2 * nb, 256, 0, stream>>>(
            cand, candCnt, rowmaxLocal, sc, ctr, out, nb, b0);
    }
}